// Round 10
// baseline (405.675 us; speedup 1.0000x reference)
//
#include <hip/hip_runtime.h>
#include <math.h>

#define ROWS 16384
#define DD   4096
#define EE   64
#define EPSF 1e-10f

#define BM    64                 // rows per gemm block -> 256 blocks
#define NS    (DD / 32 / 2)      // 64 iterations per wave (wave owns sub-half)
#define WTILE 8192               // bytes per pre-split 32-k w tile (2*4*64*16)

typedef __attribute__((ext_vector_type(8))) short short8;   // 8 bf16
typedef __attribute__((ext_vector_type(4))) float f32x4;    // MFMA C/D
typedef __attribute__((ext_vector_type(4))) unsigned u32x4; // packed bf16x8

// RNE 2-level bf16 split of 8 floats, pair-packed into 2x (4 dwords).
// a ~= a0 + a1 with |a - a0 - a1| <= 2^-18 |a|.
__device__ __forceinline__ void split2x8(const float f[8], u32x4& w0,
                                         u32x4& w1) {
#pragma unroll
  for (int i = 0; i < 4; ++i) {
    float fa = f[2 * i], fb = f[2 * i + 1];
    unsigned ua = __float_as_uint(fa), ub = __float_as_uint(fb);
    unsigned ra = ua + 0x7fffu + ((ua >> 16) & 1u);
    unsigned rb = ub + 0x7fffu + ((ub >> 16) & 1u);
    w0[i] = (rb & 0xffff0000u) | (ra >> 16);
    fa -= __uint_as_float(ra & 0xffff0000u);
    fb -= __uint_as_float(rb & 0xffff0000u);
    ua = __float_as_uint(fa); ub = __float_as_uint(fb);
    ra = ua + 0x7fffu + ((ua >> 16) & 1u);
    rb = ub + 0x7fffu + ((ub >> 16) & 1u);
    w1[i] = (rb & 0xffff0000u) | (ra >> 16);
  }
}

// ---------------------------------------------------------------------------
// One-time w pre-split (2-part) into MFMA-B-fragment-ready layout:
//   wsp[kt32][part p(2)][et(4)][lane(64)][16B]; lane reads its own 16B.
// Block 0 also zeroes g_load (stream-ordered before k_gemm's atomics).
// ---------------------------------------------------------------------------
__global__ __launch_bounds__(256) void k_wsplit(const float* __restrict__ wr,
                                                unsigned char* __restrict__ out,
                                                float* __restrict__ g_load) {
  const int kt = blockIdx.x;  // global 32-k tile 0..127
  const int t = threadIdx.x;
  const int lane = t & 63, wv = t >> 6;
  if (blockIdx.x == 0 && t < 64) g_load[t] = 0.f;
  float f[8];
  const float* wp = wr + (size_t)(kt * 32 + wv * 8) * EE + lane;
#pragma unroll
  for (int j = 0; j < 8; ++j) f[j] = wp[(size_t)j * EE];
  u32x4 w0, w1;
  split2x8(f, w0, w1);
  const int et = lane >> 4;
  const int lp = wv * 16 + (lane & 15);
  unsigned char* base = out + (size_t)kt * WTILE + et * 1024 + lp * 16;
  *(u32x4*)(base + 0 * 4096) = w0;
  *(u32x4*)(base + 1 * 4096) = w1;
}

// ---------------------------------------------------------------------------
// Router GEMM + fused softmax/expert-load -- ZERO main-loop barriers.
// 256 blocks x 512 thr (8 waves): 64 rows x 64 experts x full K=4096.
// Wave wv: m-tile mt=wv>>1 (16 rows), k-half sub=wv&1; wave processes 32-k
// subtiles k32 = 2*kt+sub, kt=0..63, all 4 e-tiles. NO LDS staging: B
// fragments load straight from wsp (already fragment-layout; 1KB/wave
// coalesced, L2-resident, m-tile twin waves hit L1); A straight to regs.
// Register double-buffer: A depth-2 (HBM latency), B depth-1 (L2 latency).
// No __syncthreads in the loop -> no lockstep, no exposed drain (the 9-round
// measured pathology: ~6k cy/phase vs ~700 cy work under drain-to-zero).
// 3-term split-product (a0b0+a0b1+a1b0), same per-wave accumulation order as
// R7 -> absmax unchanged. Epilogue: pair-wave k-sum in LDS (R7-proven).
// ---------------------------------------------------------------------------
__global__ __launch_bounds__(512) void k_gemm(
    const float* __restrict__ h, const unsigned char* __restrict__ wsp,
    float* __restrict__ logits, float* __restrict__ g_load) {
  __shared__ float sl[64 * 68 + 8 * 64];  // epilogue only (19.5 KB)

  const int t = threadIdx.x;
  const int lane = t & 63;
  const int wv = t >> 6;    // 0..7
  const int mt = wv >> 1;   // m-tile 0..3 (16 rows each)
  const int sub = wv & 1;   // k-half of each 64-k chunk
  const int row0 = blockIdx.x * BM;

  f32x4 acc[4] = {};        // 4 e-tiles, partial over this wave's k-subtiles

  // A: row = row0 + mt*16 + (lane&15), k = kt*64 + sub*32 + (lane>>4)*8 + j
  const float* ap = h + (size_t)(row0 + mt * 16 + (lane & 15)) * DD +
                    sub * 32 + (lane >> 4) * 8;
  // B: per-lane fragment address; subtile (2*kt+sub) -> + kt*16384
  const unsigned char* wb = wsp + sub * (size_t)WTILE + lane * 16;

  float4 ac0, ac1, am0, am1, an0, an1;   // A: cur / mid / next (depth-2)
  short8 bc[2][4], bn[2][4];             // B: cur / next (depth-1)

  // prologue
  ac0 = *(const float4*)(ap);
  ac1 = *(const float4*)(ap + 4);
  am0 = *(const float4*)(ap + 64);
  am1 = *(const float4*)(ap + 68);
#pragma unroll
  for (int p = 0; p < 2; ++p)
#pragma unroll
    for (int e = 0; e < 4; ++e)
      bc[p][e] = *(const short8*)(wb + p * 4096 + e * 1024);

  for (int kt = 0; kt < NS; ++kt) {
    // issue next-iteration loads (no deps on current compute)
    if (kt + 1 < NS) {
      const unsigned char* wn = wb + (size_t)(kt + 1) * 16384;
#pragma unroll
      for (int p = 0; p < 2; ++p)
#pragma unroll
        for (int e = 0; e < 4; ++e)
          bn[p][e] = *(const short8*)(wn + p * 4096 + e * 1024);
    }
    if (kt + 2 < NS) {
      const float* p4 = ap + (size_t)(kt + 2) * 64;
      an0 = *(const float4*)(p4);
      an1 = *(const float4*)(p4 + 4);
    }

    // compute current subtile
    const float af[8] = {ac0.x, ac0.y, ac0.z, ac0.w,
                         ac1.x, ac1.y, ac1.z, ac1.w};
    u32x4 q0, q1;
    split2x8(af, q0, q1);
    const short8 ah0 = __builtin_bit_cast(short8, q0);
    const short8 ah1 = __builtin_bit_cast(short8, q1);
#pragma unroll
    for (int e = 0; e < 4; ++e) {
      f32x4 c = acc[e];
      c = __builtin_amdgcn_mfma_f32_16x16x32_bf16(ah0, bc[0][e], c, 0, 0, 0);
      c = __builtin_amdgcn_mfma_f32_16x16x32_bf16(ah0, bc[1][e], c, 0, 0, 0);
      c = __builtin_amdgcn_mfma_f32_16x16x32_bf16(ah1, bc[0][e], c, 0, 0, 0);
      acc[e] = c;
    }

    // rotate buffers
    ac0 = am0; ac1 = am1; am0 = an0; am1 = an1;
#pragma unroll
    for (int p = 0; p < 2; ++p)
#pragma unroll
      for (int e = 0; e < 4; ++e) bc[p][e] = bn[p][e];
  }

  // ---- fused epilogue: pair-wave k-sum -> softmax -> load accumulation ----
  {
    const int rb = mt * 16 + (lane >> 4) * 4;     // C: row=quad*4+r
    const int cb = lane & 15;                     //    col=lane&15
    if (sub == 0) {
#pragma unroll
      for (int e = 0; e < 4; ++e)
#pragma unroll
        for (int r = 0; r < 4; ++r)
          sl[(rb + r) * 68 + e * 16 + cb] = acc[e][r];
    }
    __syncthreads();
    if (sub == 1) {
#pragma unroll
      for (int e = 0; e < 4; ++e)
#pragma unroll
        for (int r = 0; r < 4; ++r)
          sl[(rb + r) * 68 + e * 16 + cb] += acc[e][r];
    }
    __syncthreads();
  }

  float accp = 0.f;
#pragma unroll
  for (int i = 0; i < 8; ++i) {
    const int row = wv * 8 + i;
    const float x = sl[row * 68 + lane];
    float m = x;
#pragma unroll
    for (int off = 32; off > 0; off >>= 1) m = fmaxf(m, __shfl_xor(m, off, 64));
    const float p = __expf(x - m);
    float s = p;
#pragma unroll
    for (int off = 32; off > 0; off >>= 1) s += __shfl_xor(s, off, 64);
    accp += p / s;
    logits[(size_t)(row0 + row) * EE + lane] = x;   // raw logits, coalesced
  }
  float* red = sl + 64 * 68;             // disjoint LDS region
  red[wv * 64 + lane] = accp;
  __syncthreads();
  if (wv == 0) {
    float s = 0.f;
#pragma unroll
    for (int j = 0; j < 8; ++j) s += red[j * 64 + lane];
    atomicAdd(&g_load[lane], s);
  }
}

// ---------------------------------------------------------------------------
// penalty (recomputed per wave: 64-wide reduce + logf, trivially cheap)
// + adjusted logits + top-2. One row per wave.
// ---------------------------------------------------------------------------
__global__ __launch_bounds__(256) void k_top2(float* __restrict__ logits,
                                              const float* __restrict__ g_load,
                                              float* __restrict__ idx_out) {
  int t = threadIdx.x;
  int lane = t & 63;
  int wv = t >> 6;
  int row = blockIdx.x * 4 + wv;

  float v0 = g_load[lane];
  float s0 = v0;
#pragma unroll
  for (int off = 32; off > 0; off >>= 1) s0 += __shfl_xor(s0, off, 64);
  float lp = logf(v0 / (s0 * (1.f / 64.f) + EPSF) + EPSF);

  size_t base = (size_t)row * EE;
  float a = logits[base + lane] - lp;
  logits[base + lane] = a;

  float v = a;
  int idx = lane;
#pragma unroll
  for (int off = 32; off > 0; off >>= 1) {
    float ov = __shfl_xor(v, off, 64);
    int oi = __shfl_xor(idx, off, 64);
    if (ov > v || (ov == v && oi < idx)) { v = ov; idx = oi; }
  }
  int i1 = idx;

  float a2 = (lane == i1) ? -INFINITY : a;
  v = a2;
  idx = lane;
#pragma unroll
  for (int off = 32; off > 0; off >>= 1) {
    float ov = __shfl_xor(v, off, 64);
    int oi = __shfl_xor(idx, off, 64);
    if (ov > v || (ov == v && oi < idx)) { v = ov; idx = oi; }
  }
  int i2 = idx;

  if (lane == 0) {
    idx_out[(size_t)row * 2 + 0] = (float)i1;
    idx_out[(size_t)row * 2 + 1] = (float)i2;
  }
}

// ---------------------------------------------------------------------------
extern "C" void kernel_launch(void* const* d_in, const int* in_sizes, int n_in,
                              void* d_out, int out_size, void* d_ws,
                              size_t ws_size, hipStream_t stream) {
  const float* h = (const float*)d_in[0];   // [4,4096,4096]
  const float* wr = (const float*)d_in[1];  // [4096,64]
  float* out = (float*)d_out;
  float* logits = out;                          // ROWS*EE (raw, then adjusted)
  float* idx_out = out + (size_t)ROWS * EE;     // ROWS*2
  float* g_load = (float*)d_ws;                 // 64 floats
  unsigned char* wsp = (unsigned char*)d_ws + 512;  // 1 MiB pre-split w

  // no memsets: g_load zeroed in k_wsplit (stream-ordered); d_out fully
  // overwritten (logits by k_gemm stores, idx by k_top2).
  k_wsplit<<<DD / 32, 256, 0, stream>>>(wr, wsp, g_load);
  k_gemm<<<ROWS / BM, 512, 0, stream>>>(h, wsp, logits, g_load);
  k_top2<<<ROWS / 4, 256, 0, stream>>>(logits, g_load, idx_out);
}